// Round 14
// baseline (5327.423 us; speedup 1.0000x reference)
//
#include <hip/hip_runtime.h>
#include <stdint.h>

#define B_  256
#define S_  512
#define D_  64
#define H_  256
#define G3_ 768

typedef __attribute__((ext_vector_type(8))) short s8v;   // 8 bf16 (4 VGPRs)
typedef __attribute__((ext_vector_type(4))) short s4v;   // 4 bf16 (2 VGPRs)
typedef __attribute__((ext_vector_type(4))) float f4v;   // MFMA accumulator
typedef __attribute__((ext_vector_type(4))) float f4r;   // raw float4 (NT-capable)

#define MF(a, b, c) __builtin_amdgcn_mfma_f32_16x16x32_bf16((a), (b), (c), 0, 0, 0)

__device__ __forceinline__ unsigned short f2bf(float x) {  // RNE
  unsigned u = __float_as_uint(x);
  unsigned r = (u + 0x7fffu + ((u >> 16) & 1u)) >> 16;
  return (unsigned short)r;
}
__device__ __forceinline__ float bf2f(unsigned short s) {
  return __uint_as_float(((unsigned)s) << 16);
}
__device__ __forceinline__ float sigm(float x) {
  return __builtin_amdgcn_rcpf(1.f + __expf(-x));
}
__device__ __forceinline__ float tanh_f(float x) {
  return 1.f - 2.f * __builtin_amdgcn_rcpf(1.f + __expf(2.f * x));
}

// ---------------------------------------------------------------------------
// MFMA bf16-split input GEMM (3-pass, fp32-class accuracy; unchanged).
// ---------------------------------------------------------------------------
__global__ __launch_bounds__(256) void gemm_mfma(
    const float* __restrict__ A, const float* __restrict__ W,
    const float* __restrict__ bias, float* __restrict__ C,
    int K, int chsh, int t0)
{
  const int g0 = blockIdx.x * 64;
  const int r0 = blockIdx.y * 64;
  const int tid = threadIdx.x;
  const int w = tid >> 6, l = tid & 63;
  const int fr = l & 15, fq = l >> 4;

  __shared__ unsigned short Ah[64][40], Al[64][40];
  __shared__ unsigned short Wh[64][40], Wl[64][40];

  f4v acc[4] = {};

  const int row = tid >> 2, q = tid & 3;
  const int CHm1 = (1 << chsh) - 1;
  const int r = r0 + row;
  const int rg = ((r >> chsh) * S_) + t0 + (r & CHm1);
  const float* ap = A + (size_t)rg * K + q * 8;
  const float* wp = W + (size_t)(g0 + row) * K + q * 8;

  for (int k0 = 0; k0 < K; k0 += 32) {
    float4 a0 = *(const float4*)(ap + k0);
    float4 a1 = *(const float4*)(ap + k0 + 4);
    float4 w0 = *(const float4*)(wp + k0);
    float4 w1 = *(const float4*)(wp + k0 + 4);
    __syncthreads();
    float av[8] = {a0.x,a0.y,a0.z,a0.w,a1.x,a1.y,a1.z,a1.w};
    float wv[8] = {w0.x,w0.y,w0.z,w0.w,w1.x,w1.y,w1.z,w1.w};
    unsigned short ah[8], al_[8], wh[8], wl_[8];
    #pragma unroll
    for (int i = 0; i < 8; ++i) {
      ah[i]  = f2bf(av[i]);  al_[i] = f2bf(av[i] - bf2f(ah[i]));
      wh[i]  = f2bf(wv[i]);  wl_[i] = f2bf(wv[i] - bf2f(wh[i]));
    }
    *(s8v*)&Ah[row][q*8] = *(s8v*)ah;  *(s8v*)&Al[row][q*8] = *(s8v*)al_;
    *(s8v*)&Wh[row][q*8] = *(s8v*)wh;  *(s8v*)&Wl[row][q*8] = *(s8v*)wl_;
    __syncthreads();

    s8v a_hi = *(const s8v*)&Ah[w*16 + fr][fq*8];
    s8v a_lo = *(const s8v*)&Al[w*16 + fr][fq*8];
    #pragma unroll
    for (int c = 0; c < 4; ++c) {
      s8v b_hi = *(const s8v*)&Wh[c*16 + fr][fq*8];
      s8v b_lo = *(const s8v*)&Wl[c*16 + fr][fq*8];
      acc[c] = MF(a_hi, b_hi, acc[c]);
      acc[c] = MF(a_lo, b_hi, acc[c]);
      acc[c] = MF(a_hi, b_lo, acc[c]);
    }
  }

  const int orow = r0 + w * 16 + fq * 4;
  #pragma unroll
  for (int c = 0; c < 4; ++c) {
    const float bi = bias[g0 + c * 16 + fr];
    #pragma unroll
    for (int i = 0; i < 4; ++i) {
      float v = acc[c][i] + bi;
      __builtin_nontemporal_store(v, &C[(size_t)(orow + i) * G3_ + g0 + c * 16 + fr]);
    }
  }
}

// ---------------------------------------------------------------------------
// Pack W_hh into MFMA fragment order, bf16-hi only (unchanged).
// ---------------------------------------------------------------------------
__global__ __launch_bounds__(64) void pack_whh(
    const float* __restrict__ Whh, unsigned short* __restrict__ Whp)
{
  const int gti = blockIdx.x, kc = blockIdx.y, lane = threadIdx.x;
  const int row = gti * 16 + (lane & 15);
  const int k0  = kc * 32 + (lane >> 4) * 8;
  const float* src = &Whh[(size_t)row * H_ + k0];
  unsigned short hi8[8];
  #pragma unroll
  for (int s = 0; s < 8; ++s) hi8[s] = f2bf(src[s]);
  const size_t o = ((size_t)(gti * 8 + kc) * 64 + lane) * 8;
  *(s8v*)&Whp[o] = *(s8v*)hi8;
}

__global__ __launch_bounds__(768) void bias2_k(
    const float* __restrict__ bih, const float* __restrict__ bhh,
    float* __restrict__ bias2)
{
  int g = threadIdx.x;
  bias2[g] = bih[g] + (g < 512 ? bhh[g] : 0.f);
}

// ---------------------------------------------------------------------------
// MFMA GRU scan v9: 16 WGs x 512 threads (8 waves, 2/SIMD, 256-reg budget).
// Mechanical p-loop re-derivation of the verified v7 (R12) 16-wave kernel:
// each thread emulates v7's threads wid' = 2*wid + p, p = 0,1 — all formulas
// are v7's with wid -> wid'. r,z-hi resident (128 AGPR via whr0/whz0/whr1/
// whz1), n-hi in LDS (v7's exact [16 wid'][8 kc][512] 128KB layout).
// Sequential-p: 8 ahh fragments read once (32 VGPR) and shared by both
// tiles -> peak pressure ~230 regs, real margin under the 256 cap.
// Single barrier per step; Abuf[2] double buffer (16KB). Zero W stream.
// ---------------------------------------------------------------------------
__global__ __launch_bounds__(512, 2) void gru_scan(
    const float* __restrict__ gx, const unsigned short* __restrict__ Whp,
    const float* __restrict__ bhh, float* __restrict__ hbuf,
    float* __restrict__ y, int CH, int t0c, int last)
{
  const int bid = blockIdx.x;          // 16
  const int b0  = bid * 16;
  const int tid = threadIdx.x;
  const int wid = tid >> 6, lane = tid & 63;
  const int bb = lane & 15;            // batch-local (D col)
  const int fq = lane >> 4;            // row quad

  extern __shared__ unsigned short lds_[];
  unsigned short* WhN  = lds_;                 // [16 wid'][8 kc][512] = 128KB
  unsigned short* Abuf = lds_ + 65536;         // [2][8 kc][512] = 16KB

  const s8v* WhpV = (const s8v*)Whp;

  const int wid20 = 2 * wid;       // emulated v7 wave ids
  const int wid21 = 2 * wid + 1;

  // resident r,z tiles for both emulated waves (128 regs, AGPR)
  s8v whr0[8], whz0[8], whr1[8], whz1[8];
  #pragma unroll
  for (int kc = 0; kc < 8; ++kc) {
    whr0[kc] = WhpV[((     wid20) * 8 + kc) * 64 + lane];
    whz0[kc] = WhpV[((16 + wid20) * 8 + kc) * 64 + lane];
    whr1[kc] = WhpV[((     wid21) * 8 + kc) * 64 + lane];
    whz1[kc] = WhpV[((16 + wid21) * 8 + kc) * 64 + lane];
  }
  // n-hi tiles -> LDS (v7 layout: region wid')
  #pragma unroll
  for (int kc = 0; kc < 8; ++kc) {
    s8v v0 = WhpV[((32 + wid20) * 8 + kc) * 64 + lane];
    *(s8v*)&WhN[(wid20 * 8 + kc) * 512 + lane * 8] = v0;
    s8v v1 = WhpV[((32 + wid21) * 8 + kc) * 64 + lane];
    *(s8v*)&WhN[(wid21 * 8 + kc) * 512 + lane * 8] = v1;
  }

  // v7 per-thread quantities for p = 0,1
  const int u00 = 16 * wid20 + 4 * fq;
  const int u01 = 16 * wid21 + 4 * fq;

  const f4r bhn0 = *(const f4r*)&bhh[2 * H_ + u00];
  const f4r bhn1 = *(const f4r*)&bhh[2 * H_ + u01];

  f4r h0 = {0.f, 0.f, 0.f, 0.f}, h1 = {0.f, 0.f, 0.f, 0.f};
  if (t0c != 0) {
    h0 = *(const f4r*)&hbuf[(size_t)(b0 + bb) * H_ + u00];
    h1 = *(const f4r*)&hbuf[(size_t)(b0 + bb) * H_ + u01];
  }

  // v7 aoff formula, textually, with wid -> wid'
  const int aoff0 = (wid20 >> 1) * 512
      + (bb | (((2 * wid20 + (fq >> 1)) & 3) << 4)) * 8 + (fq & 1) * 4;
  const int aoff1 = (wid21 >> 1) * 512
      + (bb | (((2 * wid21 + (fq >> 1)) & 3) << 4)) * 8 + (fq & 1) * 4;

  // seed buffer 0 with bf16(h0)
  {
    s4v s0, s1;
    #pragma unroll
    for (int j = 0; j < 4; ++j) {
      s0[j] = (short)f2bf(h0[j]);
      s1[j] = (short)f2bf(h1[j]);
    }
    *(s4v*)&Abuf[aoff0] = s0;
    *(s4v*)&Abuf[aoff1] = s1;
  }

  int cur = 0;
  for (int t = 0; t < CH; ++t) {
    __syncthreads();   // bar: Abuf[cur] (and WhN at t=0) visible

    // h fragments for all kc, read once, shared by both tiles
    s8v a8[8];
    #pragma unroll
    for (int kc = 0; kc < 8; ++kc)
      a8[kc] = *(const s8v*)&Abuf[cur * 4096 + kc * 512 + lane * 8];

    // gx loads for both tiles (long distance to first use)
    const float* gb = gx + ((size_t)(b0 + bb) * CH + t) * G3_;
    f4r xr0 = __builtin_nontemporal_load((const f4r*)(gb + u00));
    f4r xz0 = __builtin_nontemporal_load((const f4r*)(gb + H_ + u00));
    f4r xn0 = __builtin_nontemporal_load((const f4r*)(gb + 2 * H_ + u00));
    f4r xr1 = __builtin_nontemporal_load((const f4r*)(gb + u01));
    f4r xz1 = __builtin_nontemporal_load((const f4r*)(gb + H_ + u01));
    f4r xn1 = __builtin_nontemporal_load((const f4r*)(gb + 2 * H_ + u01));

    // ---- emulated wave wid20 (tile p=0) ----
    {
      f4v aR = {}, aZ = {}, aN = {};
      #pragma unroll
      for (int kc = 0; kc < 8; ++kc) {
        s8v wn = *(const s8v*)&WhN[(wid20 * 8 + kc) * 512 + lane * 8];
        aR = MF(whr0[kc], a8[kc], aR);
        aZ = MF(whz0[kc], a8[kc], aZ);
        aN = MF(wn,       a8[kc], aN);
      }
      #pragma unroll
      for (int i = 0; i < 4; ++i) {
        const float r = sigm(xr0[i] + aR[i]);
        const float z = sigm(xz0[i] + aZ[i]);
        const float n = tanh_f(xn0[i] + r * (aN[i] + bhn0[i]));
        h0[i] = (1.f - z) * n + z * h0[i];
      }
      if (!last) {
        __builtin_nontemporal_store(
            h0, (f4r*)&y[((size_t)(b0 + bb) * S_ + (t0c + t)) * H_ + u00]);
      }
      s4v s0;
      #pragma unroll
      for (int j = 0; j < 4; ++j) s0[j] = (short)f2bf(h0[j]);
      *(s4v*)&Abuf[(cur ^ 1) * 4096 + aoff0] = s0;
    }

    // ---- emulated wave wid21 (tile p=1) ----
    {
      f4v aR = {}, aZ = {}, aN = {};
      #pragma unroll
      for (int kc = 0; kc < 8; ++kc) {
        s8v wn = *(const s8v*)&WhN[(wid21 * 8 + kc) * 512 + lane * 8];
        aR = MF(whr1[kc], a8[kc], aR);
        aZ = MF(whz1[kc], a8[kc], aZ);
        aN = MF(wn,       a8[kc], aN);
      }
      #pragma unroll
      for (int i = 0; i < 4; ++i) {
        const float r = sigm(xr1[i] + aR[i]);
        const float z = sigm(xz1[i] + aZ[i]);
        const float n = tanh_f(xn1[i] + r * (aN[i] + bhn1[i]));
        h1[i] = (1.f - z) * n + z * h1[i];
      }
      if (!last) {
        __builtin_nontemporal_store(
            h1, (f4r*)&y[((size_t)(b0 + bb) * S_ + (t0c + t)) * H_ + u01]);
      }
      s4v s1;
      #pragma unroll
      for (int j = 0; j < 4; ++j) s1[j] = (short)f2bf(h1[j]);
      *(s4v*)&Abuf[(cur ^ 1) * 4096 + aoff1] = s1;
    }

    cur ^= 1;
  }

  // persist h (own registers only; no barrier needed)
  *(f4r*)&hbuf[(size_t)(b0 + bb) * H_ + u00] = h0;
  *(f4r*)&hbuf[(size_t)(b0 + bb) * H_ + u01] = h1;
}

// ---------------------------------------------------------------------------
// Head: LayerNorm(h_last) -> MLP 256->32 (ReLU) -> 32->1. One wave per batch.
// ---------------------------------------------------------------------------
__global__ __launch_bounds__(64) void head_kernel(
    const float* __restrict__ hlast, const float* __restrict__ lng,
    const float* __restrict__ lnb, const float* __restrict__ W1,
    const float* __restrict__ b1, const float* __restrict__ W2,
    const float* __restrict__ b2, float* __restrict__ out)
{
  const int b = blockIdx.x;
  const int lane = threadIdx.x;
  float4 v = *(const float4*)&hlast[(size_t)b * H_ + lane * 4];
  float s = v.x + v.y + v.z + v.w;
  #pragma unroll
  for (int m = 32; m > 0; m >>= 1) s += __shfl_xor(s, m, 64);
  const float mu = s * (1.f / 256.f);
  const float dx = v.x - mu, dy = v.y - mu, dz = v.z - mu, dw = v.w - mu;
  float q = dx*dx + dy*dy + dz*dz + dw*dw;
  #pragma unroll
  for (int m = 32; m > 0; m >>= 1) q += __shfl_xor(q, m, 64);
  const float rstd = rsqrtf(q * (1.f / 256.f) + 1e-5f);

  __shared__ float ln[256];
  const int i4 = lane * 4;
  ln[i4 + 0] = dx * rstd * lng[i4 + 0] + lnb[i4 + 0];
  ln[i4 + 1] = dy * rstd * lng[i4 + 1] + lnb[i4 + 1];
  ln[i4 + 2] = dz * rstd * lng[i4 + 2] + lnb[i4 + 2];
  ln[i4 + 3] = dw * rstd * lng[i4 + 3] + lnb[i4 + 3];
  __syncthreads();

  float hd = 0.f;
  if (lane < 32) {
    const float* w = W1 + (size_t)lane * H_;
    float a = 0.f;
    for (int k = 0; k < H_; ++k) a += ln[k] * w[k];
    a += b1[lane];
    hd = fmaxf(a, 0.f) * W2[lane];
  }
  #pragma unroll
  for (int m = 16; m > 0; m >>= 1) hd += __shfl_xor(hd, m, 64);
  if (lane == 0) out[b] = hd + b2[0];
}

// ---------------------------------------------------------------------------
extern "C" void kernel_launch(void* const* d_in, const int* in_sizes, int n_in,
                              void* d_out, int out_size, void* d_ws, size_t ws_size,
                              hipStream_t stream)
{
  const float* x     = (const float*)d_in[0];
  const float* W_ih0 = (const float*)d_in[1];
  const float* W_ihr = (const float*)d_in[2];
  const float* W_hh  = (const float*)d_in[3];
  const float* b_ih  = (const float*)d_in[4];
  const float* b_hh  = (const float*)d_in[5];
  const float* lng   = (const float*)d_in[6];
  const float* lnb   = (const float*)d_in[7];
  const float* W1    = (const float*)d_in[8];
  const float* b1    = (const float*)d_in[9];
  const float* W2    = (const float*)d_in[10];
  const float* b2    = (const float*)d_in[11];
  float* out = (float*)d_out;

  const size_t y_elems   = (size_t)B_ * S_ * H_;       // 134 MB
  const size_t h_elems   = (size_t)B_ * H_;
  const size_t whp_elems = (size_t)G3_ * H_;           // bf16-hi pack

  int CH = 512;
  while (CH > 64) {
    size_t need = (y_elems + (size_t)B_ * CH * G3_ + h_elems + 768) * 4
                + whp_elems * 2 + 4096;
    if (need <= ws_size) break;
    CH >>= 1;
  }
  const int chsh = __builtin_ctz((unsigned)CH);

  float* y    = (float*)d_ws;
  float* gx   = y + y_elems;
  float* hbuf = gx + (size_t)B_ * CH * G3_;
  unsigned short* Whp = (unsigned short*)(hbuf + h_elems);
  float* bias2 = (float*)(Whp + whp_elems);

  const size_t lds_bytes = 131072 + 16384;   // 144 KiB (v7's allocation)

  for (int l = 0; l < 3; ++l) {
    const float* Wih   = (l == 0) ? W_ih0 : (W_ihr + (size_t)(l - 1) * G3_ * H_);
    const int    K     = (l == 0) ? D_ : H_;
    const float* A     = (l == 0) ? x : y;
    const float* Whh_l = W_hh + (size_t)l * G3_ * H_;
    const float* bih_l = b_ih + (size_t)l * G3_;
    const float* bhh_l = b_hh + (size_t)l * G3_;
    const int last = (l == 2) ? 1 : 0;

    bias2_k<<<1, 768, 0, stream>>>(bih_l, bhh_l, bias2);
    pack_whh<<<dim3(48, 8), 64, 0, stream>>>(Whh_l, Whp);

    for (int t0 = 0; t0 < S_; t0 += CH) {
      gemm_mfma<<<dim3(G3_ / 64, (B_ * CH) / 64), 256, 0, stream>>>(
          A, Wih, bias2, gx, K, chsh, t0);
      gru_scan<<<16, 512, lds_bytes, stream>>>(
          gx, Whp, bhh_l, hbuf, y, CH, t0, last);
    }
  }

  head_kernel<<<256, 64, 0, stream>>>(hbuf, lng, lnb, W1, b1, W2, b2, out);
}

// Round 15
// 4811.068 us; speedup vs baseline: 1.1073x; 1.1073x over previous
//
#include <hip/hip_runtime.h>
#include <stdint.h>

#define B_  256
#define S_  512
#define D_  64
#define H_  256
#define G3_ 768

typedef __attribute__((ext_vector_type(8))) short s8v;   // 8 bf16 (4 VGPRs)
typedef __attribute__((ext_vector_type(4))) short s4v;   // 4 bf16 (2 VGPRs)
typedef __attribute__((ext_vector_type(4))) float f4v;   // MFMA accumulator
typedef __attribute__((ext_vector_type(4))) float f4r;   // raw float4 (NT-capable)

#define MF(a, b, c) __builtin_amdgcn_mfma_f32_16x16x32_bf16((a), (b), (c), 0, 0, 0)

__device__ __forceinline__ unsigned short f2bf(float x) {  // RNE
  unsigned u = __float_as_uint(x);
  unsigned r = (u + 0x7fffu + ((u >> 16) & 1u)) >> 16;
  return (unsigned short)r;
}
__device__ __forceinline__ float bf2f(unsigned short s) {
  return __uint_as_float(((unsigned)s) << 16);
}
__device__ __forceinline__ float sigm(float x) {
  return __builtin_amdgcn_rcpf(1.f + __expf(-x));
}
__device__ __forceinline__ float tanh_f(float x) {
  return 1.f - 2.f * __builtin_amdgcn_rcpf(1.f + __expf(2.f * x));
}

// ---------------------------------------------------------------------------
// Single-pass bf16 MFMA input GEMM: C[r,g] = sum_k A[rowmap(r),k]*W[g,k]+b[g].
// Both operands bf16 (consistent with the scan's W-hi precision; error margin
// verified ~3x under threshold). 4 MFMA per K-step, half staging VALU/LDS.
// ---------------------------------------------------------------------------
__global__ __launch_bounds__(256) void gemm_mfma(
    const float* __restrict__ A, const float* __restrict__ W,
    const float* __restrict__ bias, float* __restrict__ C,
    int K, int chsh, int t0)
{
  const int g0 = blockIdx.x * 64;
  const int r0 = blockIdx.y * 64;
  const int tid = threadIdx.x;
  const int w = tid >> 6, l = tid & 63;
  const int fr = l & 15, fq = l >> 4;

  __shared__ unsigned short Ah[64][40];
  __shared__ unsigned short Wh[64][40];

  f4v acc[4] = {};

  const int row = tid >> 2, q = tid & 3;
  const int CHm1 = (1 << chsh) - 1;
  const int r = r0 + row;
  const int rg = ((r >> chsh) * S_) + t0 + (r & CHm1);
  const float* ap = A + (size_t)rg * K + q * 8;
  const float* wp = W + (size_t)(g0 + row) * K + q * 8;

  for (int k0 = 0; k0 < K; k0 += 32) {
    float4 a0 = *(const float4*)(ap + k0);
    float4 a1 = *(const float4*)(ap + k0 + 4);
    float4 w0 = *(const float4*)(wp + k0);
    float4 w1 = *(const float4*)(wp + k0 + 4);
    __syncthreads();
    float av[8] = {a0.x,a0.y,a0.z,a0.w,a1.x,a1.y,a1.z,a1.w};
    float wv[8] = {w0.x,w0.y,w0.z,w0.w,w1.x,w1.y,w1.z,w1.w};
    unsigned short ah[8], wh[8];
    #pragma unroll
    for (int i = 0; i < 8; ++i) {
      ah[i] = f2bf(av[i]);
      wh[i] = f2bf(wv[i]);
    }
    *(s8v*)&Ah[row][q*8] = *(s8v*)ah;
    *(s8v*)&Wh[row][q*8] = *(s8v*)wh;
    __syncthreads();

    s8v a_hi = *(const s8v*)&Ah[w*16 + fr][fq*8];
    #pragma unroll
    for (int c = 0; c < 4; ++c) {
      s8v b_hi = *(const s8v*)&Wh[c*16 + fr][fq*8];
      acc[c] = MF(a_hi, b_hi, acc[c]);
    }
  }

  const int orow = r0 + w * 16 + fq * 4;
  #pragma unroll
  for (int c = 0; c < 4; ++c) {
    const float bi = bias[g0 + c * 16 + fr];
    #pragma unroll
    for (int i = 0; i < 4; ++i) {
      float v = acc[c][i] + bi;
      __builtin_nontemporal_store(v, &C[(size_t)(orow + i) * G3_ + g0 + c * 16 + fr]);
    }
  }
}

// ---------------------------------------------------------------------------
// Pack W_hh into MFMA fragment order (bf16-hi) + fold biases (block 0,0).
// ---------------------------------------------------------------------------
__global__ __launch_bounds__(64) void pack_whh(
    const float* __restrict__ Whh, unsigned short* __restrict__ Whp,
    const float* __restrict__ bih, const float* __restrict__ bhh,
    float* __restrict__ bias2)
{
  const int gti = blockIdx.x, kc = blockIdx.y, lane = threadIdx.x;
  const int rowp = gti * 16 + (lane & 15);
  const int k0  = kc * 32 + (lane >> 4) * 8;
  const float* src = &Whh[(size_t)rowp * H_ + k0];
  unsigned short hi8[8];
  #pragma unroll
  for (int s = 0; s < 8; ++s) hi8[s] = f2bf(src[s]);
  const size_t o = ((size_t)(gti * 8 + kc) * 64 + lane) * 8;
  *(s8v*)&Whp[o] = *(s8v*)hi8;

  if (gti == 0 && kc == 0) {
    #pragma unroll
    for (int i = 0; i < 12; ++i) {
      int g = i * 64 + lane;
      bias2[g] = bih[g] + (g < 512 ? bhh[g] : 0.f);
    }
  }
}

// ---------------------------------------------------------------------------
// MFMA GRU scan v7 (verified R12 kernel, byte-identical): SINGLE barrier per
// step; epilogue writes bf16(h) directly into double-buffered Abuf; r,z-hi
// resident in 64 regs; n-hi in LDS (128KB). 16 WGs x 1024 threads.
// ---------------------------------------------------------------------------
__global__ __launch_bounds__(1024, 4) void gru_scan(
    const float* __restrict__ gx, const unsigned short* __restrict__ Whp,
    const float* __restrict__ bhh, float* __restrict__ hbuf,
    float* __restrict__ y, int CH, int t0c, int last)
{
  const int bid = blockIdx.x;          // 16
  const int b0  = bid * 16;
  const int tid = threadIdx.x;
  const int wid = tid >> 6, lane = tid & 63;
  const int bb = lane & 15;            // batch-local (D col)
  const int fq = lane >> 4;            // row quad (D rows 4fq..4fq+3)

  extern __shared__ unsigned short lds_[];
  unsigned short* WhN  = lds_;                 // [16 w][8 kc][512] = 128KB
  unsigned short* Abuf = lds_ + 65536;         // [2][8 kc][512] = 16KB

  const s8v* WhpV = (const s8v*)Whp;

  // resident r-hi, z-hi tiles (64 regs -> within the 128/wave cap)
  s8v whr[8], whz[8];
  #pragma unroll
  for (int kc = 0; kc < 8; ++kc) {
    whr[kc] = WhpV[((     wid) * 8 + kc) * 64 + lane];
    whz[kc] = WhpV[((16 + wid) * 8 + kc) * 64 + lane];
  }
  // n-hi tile -> LDS (each wave its own 8KB region)
  #pragma unroll
  for (int kc = 0; kc < 8; ++kc) {
    s8v v = WhpV[((32 + wid) * 8 + kc) * 64 + lane];
    *(s8v*)&WhN[(wid * 8 + kc) * 512 + lane * 8] = v;
  }

  const int u0 = 16 * wid + 4 * fq;        // own unit quad
  const f4r bhn4 = *(const f4r*)&bhh[2 * H_ + u0];

  // h state in registers
  f4r hn4 = {0.f, 0.f, 0.f, 0.f};
  if (t0c != 0) hn4 = *(const f4r*)&hbuf[(size_t)(b0 + bb) * H_ + u0];

  // static (unit,batch) -> A-frag slot mapping for this thread's h quad
  const int kcw  = wid >> 1;                              // u0 >> 5
  const int lp   = bb | (((2 * wid + (fq >> 1)) & 3) << 4);
  const int eo   = (fq & 1) * 4;                          // u0 & 7
  const int aoff = kcw * 512 + lp * 8 + eo;

  // seed buffer 0 with bf16(h0)
  {
    s4v hh;
    #pragma unroll
    for (int j = 0; j < 4; ++j) hh[j] = (short)f2bf(hn4[j]);
    *(s4v*)&Abuf[aoff] = hh;
  }

  int cur = 0;
  for (int t = 0; t < CH; ++t) {
    __syncthreads();   // bar: Abuf[cur] (and WhN at t=0) visible to all

    // gx loads (used only in epilogue; latency hides under MFMA loop)
    const float* gb = gx + ((size_t)(b0 + bb) * CH + t) * G3_;
    f4r xr4 = __builtin_nontemporal_load((const f4r*)(gb + u0));
    f4r xz4 = __builtin_nontemporal_load((const f4r*)(gb + H_ + u0));
    f4r xn4 = __builtin_nontemporal_load((const f4r*)(gb + 2 * H_ + u0));

    f4v accR = {}, accZ = {}, accN = {};
    #pragma unroll
    for (int kc = 0; kc < 8; ++kc) {
      s8v ahh = *(const s8v*)&Abuf[cur * 4096 + kc * 512 + lane * 8];
      s8v wn  = *(const s8v*)&WhN[(wid * 8 + kc) * 512 + lane * 8];
      accR = MF(whr[kc], ahh, accR);
      accZ = MF(whz[kc], ahh, accZ);
      accN = MF(wn,      ahh, accN);
    }

    // epilogue: gate math; y store from regs; publish bf16(h) to Abuf[cur^1]
    #pragma unroll
    for (int i = 0; i < 4; ++i) {
      const float r = sigm(xr4[i] + accR[i]);
      const float z = sigm(xz4[i] + accZ[i]);
      const float n = tanh_f(xn4[i] + r * (accN[i] + bhn4[i]));
      hn4[i] = (1.f - z) * n + z * hn4[i];
    }
    if (!last) {
      __builtin_nontemporal_store(
          hn4, (f4r*)&y[((size_t)(b0 + bb) * S_ + (t0c + t)) * H_ + u0]);
    }
    {
      s4v hh;
      #pragma unroll
      for (int j = 0; j < 4; ++j) hh[j] = (short)f2bf(hn4[j]);
      *(s4v*)&Abuf[(cur ^ 1) * 4096 + aoff] = hh;
    }
    cur ^= 1;
  }

  // persist h
  *(f4r*)&hbuf[(size_t)(b0 + bb) * H_ + u0] = hn4;
}

// ---------------------------------------------------------------------------
// Head: LayerNorm(h_last) -> MLP 256->32 (ReLU) -> 32->1. One wave per batch.
// ---------------------------------------------------------------------------
__global__ __launch_bounds__(64) void head_kernel(
    const float* __restrict__ hlast, const float* __restrict__ lng,
    const float* __restrict__ lnb, const float* __restrict__ W1,
    const float* __restrict__ b1, const float* __restrict__ W2,
    const float* __restrict__ b2, float* __restrict__ out)
{
  const int b = blockIdx.x;
  const int lane = threadIdx.x;
  float4 v = *(const float4*)&hlast[(size_t)b * H_ + lane * 4];
  float s = v.x + v.y + v.z + v.w;
  #pragma unroll
  for (int m = 32; m > 0; m >>= 1) s += __shfl_xor(s, m, 64);
  const float mu = s * (1.f / 256.f);
  const float dx = v.x - mu, dy = v.y - mu, dz = v.z - mu, dw = v.w - mu;
  float q = dx*dx + dy*dy + dz*dz + dw*dw;
  #pragma unroll
  for (int m = 32; m > 0; m >>= 1) q += __shfl_xor(q, m, 64);
  const float rstd = rsqrtf(q * (1.f / 256.f) + 1e-5f);

  __shared__ float ln[256];
  const int i4 = lane * 4;
  ln[i4 + 0] = dx * rstd * lng[i4 + 0] + lnb[i4 + 0];
  ln[i4 + 1] = dy * rstd * lng[i4 + 1] + lnb[i4 + 1];
  ln[i4 + 2] = dz * rstd * lng[i4 + 2] + lnb[i4 + 2];
  ln[i4 + 3] = dw * rstd * lng[i4 + 3] + lnb[i4 + 3];
  __syncthreads();

  float hd = 0.f;
  if (lane < 32) {
    const float* w = W1 + (size_t)lane * H_;
    float a = 0.f;
    for (int k = 0; k < H_; ++k) a += ln[k] * w[k];
    a += b1[lane];
    hd = fmaxf(a, 0.f) * W2[lane];
  }
  #pragma unroll
  for (int m = 16; m > 0; m >>= 1) hd += __shfl_xor(hd, m, 64);
  if (lane == 0) out[b] = hd + b2[0];
}

// ---------------------------------------------------------------------------
extern "C" void kernel_launch(void* const* d_in, const int* in_sizes, int n_in,
                              void* d_out, int out_size, void* d_ws, size_t ws_size,
                              hipStream_t stream)
{
  const float* x     = (const float*)d_in[0];
  const float* W_ih0 = (const float*)d_in[1];
  const float* W_ihr = (const float*)d_in[2];
  const float* W_hh  = (const float*)d_in[3];
  const float* b_ih  = (const float*)d_in[4];
  const float* b_hh  = (const float*)d_in[5];
  const float* lng   = (const float*)d_in[6];
  const float* lnb   = (const float*)d_in[7];
  const float* W1    = (const float*)d_in[8];
  const float* b1    = (const float*)d_in[9];
  const float* W2    = (const float*)d_in[10];
  const float* b2    = (const float*)d_in[11];
  float* out = (float*)d_out;

  const size_t y_elems   = (size_t)B_ * S_ * H_;       // 134 MB
  const size_t h_elems   = (size_t)B_ * H_;
  const size_t whp_elems = (size_t)G3_ * H_;           // bf16-hi pack

  int CH = 512;
  while (CH > 64) {
    size_t need = (y_elems + (size_t)B_ * CH * G3_ + h_elems + 768) * 4
                + whp_elems * 2 + 4096;
    if (need <= ws_size) break;
    CH >>= 1;
  }
  const int chsh = __builtin_ctz((unsigned)CH);

  float* y    = (float*)d_ws;
  float* gx   = y + y_elems;
  float* hbuf = gx + (size_t)B_ * CH * G3_;
  unsigned short* Whp = (unsigned short*)(hbuf + h_elems);
  float* bias2 = (float*)(Whp + whp_elems);

  const size_t lds_bytes = 131072 + 16384;   // 144 KiB

  for (int l = 0; l < 3; ++l) {
    const float* Wih   = (l == 0) ? W_ih0 : (W_ihr + (size_t)(l - 1) * G3_ * H_);
    const int    K     = (l == 0) ? D_ : H_;
    const float* A     = (l == 0) ? x : y;
    const float* Whh_l = W_hh + (size_t)l * G3_ * H_;
    const float* bih_l = b_ih + (size_t)l * G3_;
    const float* bhh_l = b_hh + (size_t)l * G3_;
    const int last = (l == 2) ? 1 : 0;

    pack_whh<<<dim3(48, 8), 64, 0, stream>>>(Whh_l, Whp, bih_l, bhh_l, bias2);

    for (int t0 = 0; t0 < S_; t0 += CH) {
      gemm_mfma<<<dim3(G3_ / 64, (B_ * CH) / 64), 256, 0, stream>>>(
          A, Wih, bias2, gx, K, chsh, t0);
      gru_scan<<<16, 1024, lds_bytes, stream>>>(
          gx, Whp, bhh_l, hbuf, y, CH, t0, last);
    }
  }

  head_kernel<<<256, 64, 0, stream>>>(hbuf, lng, lnb, W1, b1, W2, b2, out);
}

// Round 16
// 3359.385 us; speedup vs baseline: 1.5858x; 1.4321x over previous
//
#include <hip/hip_runtime.h>
#include <stdint.h>

#define B_  256
#define S_  512
#define D_  64
#define H_  256
#define G3_ 768

typedef __attribute__((ext_vector_type(8))) short s8v;   // 8 bf16 (4 VGPRs)
typedef __attribute__((ext_vector_type(4))) short s4v;   // 4 bf16 (2 VGPRs)
typedef __attribute__((ext_vector_type(4))) float f4v;   // MFMA accumulator
typedef __attribute__((ext_vector_type(4))) float f4r;   // raw float4

#define MF(a, b, c) __builtin_amdgcn_mfma_f32_16x16x32_bf16((a), (b), (c), 0, 0, 0)

__device__ __forceinline__ unsigned short f2bf(float x) {  // RNE
  unsigned u = __float_as_uint(x);
  unsigned r = (u + 0x7fffu + ((u >> 16) & 1u)) >> 16;
  return (unsigned short)r;
}
__device__ __forceinline__ float sigm(float x) {
  return __builtin_amdgcn_rcpf(1.f + __expf(-x));
}
__device__ __forceinline__ float tanh_f(float x) {
  return 1.f - 2.f * __builtin_amdgcn_rcpf(1.f + __expf(2.f * x));
}

// ---------------------------------------------------------------------------
// Pack W_hh into MFMA fragment order (bf16-hi) + fold biases (block 0,0).
// ---------------------------------------------------------------------------
__global__ __launch_bounds__(64) void pack_whh(
    const float* __restrict__ Whh, unsigned short* __restrict__ Whp,
    const float* __restrict__ bih, const float* __restrict__ bhh,
    float* __restrict__ bias2)
{
  const int gti = blockIdx.x, kc = blockIdx.y, lane = threadIdx.x;
  const int rowp = gti * 16 + (lane & 15);
  const int k0  = kc * 32 + (lane >> 4) * 8;
  const float* src = &Whh[(size_t)rowp * H_ + k0];
  unsigned short hi8[8];
  #pragma unroll
  for (int s = 0; s < 8; ++s) hi8[s] = f2bf(src[s]);
  const size_t o = ((size_t)(gti * 8 + kc) * 64 + lane) * 8;
  *(s8v*)&Whp[o] = *(s8v*)hi8;

  if (gti == 0 && kc == 0) {
    #pragma unroll
    for (int i = 0; i < 12; ++i) {
      int g = i * 64 + lane;
      bias2[g] = bih[g] + (g < 512 ? bhh[g] : 0.f);
    }
  }
}

// ---------------------------------------------------------------------------
// Fused pipeline dispatch. Blocks [0,16): GRU scan for chunk k (verified R12
// kernel). Blocks [16, 16+CH*12): single-pass bf16 gemm for chunk k+1 into
// the other gx buffer. No intra-dispatch dependency between roles; dispatch
// boundaries carry all ordering. 1024 threads both roles; LDS 144KB.
// ---------------------------------------------------------------------------
__global__ __launch_bounds__(1024, 4) void fused_step(
    // scan role
    const float* __restrict__ gx_r, const unsigned short* __restrict__ Whp_s,
    const float* __restrict__ bhh_s, float* __restrict__ hbuf,
    float* __restrict__ y, int CH, int chsh, int t0s, int lastL, int do_scan,
    // gemm role
    const float* __restrict__ A, const float* __restrict__ Wih,
    const float* __restrict__ bias2g, float* __restrict__ gx_w,
    int K, int t0g, int do_gemm)
{
  const int tid = threadIdx.x;
  const int wid = tid >> 6, lane = tid & 63;
  const int fr = lane & 15, fq = lane >> 4;

  extern __shared__ unsigned short lds_[];

  if (blockIdx.x < 16) {
    // ===================== SCAN ROLE (R12 kernel, CH param) ================
    if (!do_scan) return;
    unsigned short* WhN  = lds_;                 // [16 w][8 kc][512] = 128KB
    unsigned short* Abuf = lds_ + 65536;         // [2][8 kc][512] = 16KB

    const int bid = blockIdx.x;
    const int b0  = bid * 16;
    const int bb  = fr;                          // lane & 15

    const s8v* WhpV = (const s8v*)Whp_s;

    s8v whr[8], whz[8];
    #pragma unroll
    for (int kc = 0; kc < 8; ++kc) {
      whr[kc] = WhpV[((     wid) * 8 + kc) * 64 + lane];
      whz[kc] = WhpV[((16 + wid) * 8 + kc) * 64 + lane];
    }
    #pragma unroll
    for (int kc = 0; kc < 8; ++kc) {
      s8v v = WhpV[((32 + wid) * 8 + kc) * 64 + lane];
      *(s8v*)&WhN[(wid * 8 + kc) * 512 + lane * 8] = v;
    }

    const int u0 = 16 * wid + 4 * fq;
    const f4r bhn4 = *(const f4r*)&bhh_s[2 * H_ + u0];

    f4r hn4 = {0.f, 0.f, 0.f, 0.f};
    if (t0s != 0) hn4 = *(const f4r*)&hbuf[(size_t)(b0 + bb) * H_ + u0];

    const int kcw  = wid >> 1;
    const int lp   = bb | (((2 * wid + (fq >> 1)) & 3) << 4);
    const int eo   = (fq & 1) * 4;
    const int aoff = kcw * 512 + lp * 8 + eo;

    {
      s4v hh;
      #pragma unroll
      for (int j = 0; j < 4; ++j) hh[j] = (short)f2bf(hn4[j]);
      *(s4v*)&Abuf[aoff] = hh;
    }

    int cur = 0;
    for (int t = 0; t < CH; ++t) {
      __syncthreads();   // Abuf[cur] (and WhN at t=0) visible

      // gx loads: regular (L2/L3-hot from previous dispatch's gemm)
      const float* gb = gx_r + ((size_t)(b0 + bb) * CH + t) * G3_;
      f4r xr4 = *(const f4r*)(gb + u0);
      f4r xz4 = *(const f4r*)(gb + H_ + u0);
      f4r xn4 = *(const f4r*)(gb + 2 * H_ + u0);

      f4v accR = {}, accZ = {}, accN = {};
      #pragma unroll
      for (int kc = 0; kc < 8; ++kc) {
        s8v ahh = *(const s8v*)&Abuf[cur * 4096 + kc * 512 + lane * 8];
        s8v wn  = *(const s8v*)&WhN[(wid * 8 + kc) * 512 + lane * 8];
        accR = MF(whr[kc], ahh, accR);
        accZ = MF(whz[kc], ahh, accZ);
        accN = MF(wn,      ahh, accN);
      }

      #pragma unroll
      for (int i = 0; i < 4; ++i) {
        const float r = sigm(xr4[i] + accR[i]);
        const float z = sigm(xz4[i] + accZ[i]);
        const float n = tanh_f(xn4[i] + r * (accN[i] + bhn4[i]));
        hn4[i] = (1.f - z) * n + z * hn4[i];
      }
      if (!lastL) {
        __builtin_nontemporal_store(
            hn4, (f4r*)&y[((size_t)(b0 + bb) * S_ + (t0s + t)) * H_ + u0]);
      }
      {
        s4v hh;
        #pragma unroll
        for (int j = 0; j < 4; ++j) hh[j] = (short)f2bf(hn4[j]);
        *(s4v*)&Abuf[(cur ^ 1) * 4096 + aoff] = hh;
      }
      cur ^= 1;
    }

    *(f4r*)&hbuf[(size_t)(b0 + bb) * H_ + u0] = hn4;

  } else {
    // ===================== GEMM ROLE (chunk k+1) ===========================
    if (!do_gemm) return;
    // LDS: Ah [256][40] ushort (20480 B) + Wh [64][40] (5120 B)
    unsigned short* Ah = lds_;            // stride 40
    unsigned short* Wh = lds_ + 10240;

    const int gb2 = blockIdx.x - 16;
    const int mtile = gb2 / 12, gtile = gb2 % 12;   // mtile-major: A-tile L2 reuse
    const int r0 = mtile * 256, g0 = gtile * 64;

    const int row = tid >> 2;              // 0..255
    const int ks  = (tid & 3) * 8;
    const int CHm1 = CH - 1;
    const int r = r0 + row;
    const int rg = ((r >> chsh) * S_) + t0g + (r & CHm1);
    const float* ap = A + (size_t)rg * K + ks;
    const float* wp = Wih + (size_t)(g0 + (tid >> 2 & 63)) * K + ks;  // rows 0..63 for tid<256

    f4v acc[4] = {};

    for (int k0 = 0; k0 < K; k0 += 32) {
      float4 a0 = *(const float4*)(ap + k0);
      float4 a1 = *(const float4*)(ap + k0 + 4);
      float4 w0, w1;
      if (tid < 256) {
        w0 = *(const float4*)(wp + k0);
        w1 = *(const float4*)(wp + k0 + 4);
      }
      __syncthreads();   // prev frag reads done
      {
        float av[8] = {a0.x,a0.y,a0.z,a0.w,a1.x,a1.y,a1.z,a1.w};
        unsigned short ah8[8];
        #pragma unroll
        for (int i = 0; i < 8; ++i) ah8[i] = f2bf(av[i]);
        *(s8v*)&Ah[row * 40 + ks] = *(s8v*)ah8;
        if (tid < 256) {
          float wv[8] = {w0.x,w0.y,w0.z,w0.w,w1.x,w1.y,w1.z,w1.w};
          unsigned short wh8[8];
          #pragma unroll
          for (int i = 0; i < 8; ++i) wh8[i] = f2bf(wv[i]);
          *(s8v*)&Wh[(tid >> 2) * 40 + ks] = *(s8v*)wh8;
        }
      }
      __syncthreads();

      s8v a_hi = *(const s8v*)&Ah[(16 * wid + fr) * 40 + fq * 8];
      #pragma unroll
      for (int c = 0; c < 4; ++c) {
        s8v b_hi = *(const s8v*)&Wh[(c * 16 + fr) * 40 + fq * 8];
        acc[c] = MF(a_hi, b_hi, acc[c]);
      }
    }

    const int orow = r0 + wid * 16 + fq * 4;
    #pragma unroll
    for (int c = 0; c < 4; ++c) {
      const float bi = bias2g[g0 + c * 16 + fr];
      #pragma unroll
      for (int i = 0; i < 4; ++i) {
        gx_w[(size_t)(orow + i) * G3_ + g0 + c * 16 + fr] = acc[c][i] + bi;
      }
    }
  }
}

// ---------------------------------------------------------------------------
// Head: LayerNorm(h_last) -> MLP 256->32 (ReLU) -> 32->1. One wave per batch.
// ---------------------------------------------------------------------------
__global__ __launch_bounds__(64) void head_kernel(
    const float* __restrict__ hlast, const float* __restrict__ lng,
    const float* __restrict__ lnb, const float* __restrict__ W1,
    const float* __restrict__ b1, const float* __restrict__ W2,
    const float* __restrict__ b2, float* __restrict__ out)
{
  const int b = blockIdx.x;
  const int lane = threadIdx.x;
  float4 v = *(const float4*)&hlast[(size_t)b * H_ + lane * 4];
  float s = v.x + v.y + v.z + v.w;
  #pragma unroll
  for (int m = 32; m > 0; m >>= 1) s += __shfl_xor(s, m, 64);
  const float mu = s * (1.f / 256.f);
  const float dx = v.x - mu, dy = v.y - mu, dz = v.z - mu, dw = v.w - mu;
  float q = dx*dx + dy*dy + dz*dz + dw*dw;
  #pragma unroll
  for (int m = 32; m > 0; m >>= 1) q += __shfl_xor(q, m, 64);
  const float rstd = rsqrtf(q * (1.f / 256.f) + 1e-5f);

  __shared__ float ln[256];
  const int i4 = lane * 4;
  ln[i4 + 0] = dx * rstd * lng[i4 + 0] + lnb[i4 + 0];
  ln[i4 + 1] = dy * rstd * lng[i4 + 1] + lnb[i4 + 1];
  ln[i4 + 2] = dz * rstd * lng[i4 + 2] + lnb[i4 + 2];
  ln[i4 + 3] = dw * rstd * lng[i4 + 3] + lnb[i4 + 3];
  __syncthreads();

  float hd = 0.f;
  if (lane < 32) {
    const float* w = W1 + (size_t)lane * H_;
    float a = 0.f;
    for (int k = 0; k < H_; ++k) a += ln[k] * w[k];
    a += b1[lane];
    hd = fmaxf(a, 0.f) * W2[lane];
  }
  #pragma unroll
  for (int m = 16; m > 0; m >>= 1) hd += __shfl_xor(hd, m, 64);
  if (lane == 0) out[b] = hd + b2[0];
}

// ---------------------------------------------------------------------------
extern "C" void kernel_launch(void* const* d_in, const int* in_sizes, int n_in,
                              void* d_out, int out_size, void* d_ws, size_t ws_size,
                              hipStream_t stream)
{
  const float* x     = (const float*)d_in[0];
  const float* W_ih0 = (const float*)d_in[1];
  const float* W_ihr = (const float*)d_in[2];
  const float* W_hh  = (const float*)d_in[3];
  const float* b_ih  = (const float*)d_in[4];
  const float* b_hh  = (const float*)d_in[5];
  const float* lng   = (const float*)d_in[6];
  const float* lnb   = (const float*)d_in[7];
  const float* W1    = (const float*)d_in[8];
  const float* b1    = (const float*)d_in[9];
  const float* W2    = (const float*)d_in[10];
  const float* b2    = (const float*)d_in[11];
  float* out = (float*)d_out;

  const size_t y_elems   = (size_t)B_ * S_ * H_;
  const size_t h_elems   = (size_t)B_ * H_;
  const size_t whp_elems = (size_t)G3_ * H_;           // per-layer bf16 pack

  // pick CH so y + 2*gx(CH) + hbuf + 3*Whp + 3*bias2 fits
  int CH = 64;
  while (CH > 8) {
    size_t need = (y_elems + 2 * (size_t)B_ * CH * G3_ + h_elems + 3 * 768) * 4
                + 3 * whp_elems * 2 + 4096;
    if (need <= ws_size) break;
    CH >>= 1;
  }
  const int chsh = __builtin_ctz((unsigned)CH);
  const size_t gx_elems = (size_t)B_ * CH * G3_;
  const int cpl = S_ / CH;           // chunks per layer
  const int NC  = 3 * cpl;           // total chunks

  float* y    = (float*)d_ws;
  float* gx0  = y + y_elems;
  float* gx1  = gx0 + gx_elems;
  float* hbuf = gx1 + gx_elems;
  unsigned short* Whp = (unsigned short*)(hbuf + h_elems);
  float* bias2 = (float*)(Whp + 3 * whp_elems);

  const size_t lds_bytes = 131072 + 16384;   // 144 KiB
  const int grid = 16 + CH * 12;             // 16 scan + (B*CH/256)*12 gemm

  // pack all layers upfront (per-layer Whp/bias2 -> no WAR hazards)
  for (int l = 0; l < 3; ++l) {
    pack_whh<<<dim3(48, 8), 64, 0, stream>>>(
        W_hh + (size_t)l * G3_ * H_, Whp + (size_t)l * whp_elems,
        b_ih + (size_t)l * G3_, b_hh + (size_t)l * G3_, bias2 + l * 768);
  }

  float* gxb[2] = { gx0, gx1 };

  // helper lambdas for per-chunk params
  auto gemm_args = [&](int k) {
    struct { const float* A; const float* Wih; const float* b2g; int K; int t0; } a;
    const int l = k / cpl, c = k % cpl;
    a.A   = (l == 0) ? x : y;
    a.Wih = (l == 0) ? W_ih0 : (W_ihr + (size_t)(l - 1) * G3_ * H_);
    a.b2g = bias2 + l * 768;
    a.K   = (l == 0) ? D_ : H_;
    a.t0  = c * CH;
    return a;
  };

  // prologue: gemm-only for chunk 0
  {
    auto g = gemm_args(0);
    fused_step<<<grid, 1024, lds_bytes, stream>>>(
        nullptr, nullptr, nullptr, nullptr, nullptr, CH, chsh, 0, 0, /*do_scan=*/0,
        g.A, g.Wih, g.b2g, gxb[0], g.K, g.t0, /*do_gemm=*/1);
  }

  for (int k = 0; k < NC; ++k) {
    const int l = k / cpl, c = k % cpl;
    const int lastL = (l == 2) ? 1 : 0;
    const unsigned short* Whp_l = Whp + (size_t)l * whp_elems;
    const float* bhh_l = b_hh + (size_t)l * G3_;

    const int kn = k + 1;
    const int do_g = (kn < NC) ? 1 : 0;
    auto g = gemm_args(do_g ? kn : 0);

    fused_step<<<grid, 1024, lds_bytes, stream>>>(
        gxb[k & 1], Whp_l, bhh_l, hbuf, y, CH, chsh, c * CH, lastL, /*do_scan=*/1,
        g.A, g.Wih, g.b2g, gxb[kn & 1], g.K, g.t0, do_g);
  }

  head_kernel<<<256, 64, 0, stream>>>(hbuf, lng, lnb, W1, b1, W2, b2, out);
}

// Round 17
// 1579.655 us; speedup vs baseline: 3.3725x; 2.1267x over previous
//
#include <hip/hip_runtime.h>
#include <stdint.h>

#define B_  256
#define S_  512
#define D_  64
#define H_  256
#define G3_ 768

typedef __attribute__((ext_vector_type(8))) short s8v;   // 8 bf16 (4 VGPRs)
typedef __attribute__((ext_vector_type(4))) short s4v;   // 4 bf16 (2 VGPRs)
typedef __attribute__((ext_vector_type(4))) float f4v;   // MFMA accumulator
typedef __attribute__((ext_vector_type(4))) float f4r;   // raw float4

#define MF(a, b, c) __builtin_amdgcn_mfma_f32_16x16x32_bf16((a), (b), (c), 0, 0, 0)

__device__ __forceinline__ unsigned short f2bf(float x) {  // RNE
  unsigned u = __float_as_uint(x);
  unsigned r = (u + 0x7fffu + ((u >> 16) & 1u)) >> 16;
  return (unsigned short)r;
}
__device__ __forceinline__ float sigm(float x) {
  return __builtin_amdgcn_rcpf(1.f + __expf(-x));
}
__device__ __forceinline__ float tanh_f(float x) {
  return 1.f - 2.f * __builtin_amdgcn_rcpf(1.f + __expf(2.f * x));
}

// ---------------------------------------------------------------------------
// Pack W_hh into MFMA fragment order (bf16-hi) + fold biases (block 0,0).
// ---------------------------------------------------------------------------
__global__ __launch_bounds__(64) void pack_whh(
    const float* __restrict__ Whh, unsigned short* __restrict__ Whp,
    const float* __restrict__ bih, const float* __restrict__ bhh,
    float* __restrict__ bias2)
{
  const int gti = blockIdx.x, kc = blockIdx.y, lane = threadIdx.x;
  const int rowp = gti * 16 + (lane & 15);
  const int k0  = kc * 32 + (lane >> 4) * 8;
  const float* src = &Whh[(size_t)rowp * H_ + k0];
  unsigned short hi8[8];
  #pragma unroll
  for (int s = 0; s < 8; ++s) hi8[s] = f2bf(src[s]);
  const size_t o = ((size_t)(gti * 8 + kc) * 64 + lane) * 8;
  *(s8v*)&Whp[o] = *(s8v*)hi8;

  if (gti == 0 && kc == 0) {
    #pragma unroll
    for (int i = 0; i < 12; ++i) {
      int g = i * 64 + lane;
      bias2[g] = bih[g] + (g < 512 ? bhh[g] : 0.f);
    }
  }
}

// ---------------------------------------------------------------------------
// Layer-pipelined fused dispatch for slot s.
//   Blocks [0,48): scan role — block b runs scan(l = b/16, chunk c = s-2l)
//     if 0 <= c < cpl. 16 WGs per active layer; per-layer Whp/hbuf/gx.
//   Blocks [48, 48+3*CH*12): gemm role — slice l computes gemm(l, c2=s+1-2l)
//     into gx[l][c2&1] if 0 <= c2 < cpl.
// Dependency chain (verified): gemm(l,c) slot c+2l-1 -> scan(l,c) slot c+2l;
// scan(l,c) overwrites y region c one slot AFTER its only reader gemm(l+1,c).
// All ordering via dispatch boundaries; no cross-WG sync anywhere.
// ---------------------------------------------------------------------------
__global__ __launch_bounds__(1024, 4) void fused_step(
    int s, int CH, int chsh, int cpl,
    const float* __restrict__ x, float* __restrict__ y,
    const float* __restrict__ W_ih0, const float* __restrict__ W_ihr,
    const unsigned short* __restrict__ Whp, const float* __restrict__ bhh_all,
    const float* __restrict__ bias2, float* __restrict__ gxbase,
    float* __restrict__ hbuf)
{
  const int tid = threadIdx.x;
  const int wid = tid >> 6, lane = tid & 63;
  const int fr = lane & 15, fq = lane >> 4;
  const size_t gx_elems = (size_t)B_ * CH * G3_;

  extern __shared__ unsigned short lds_[];

  if (blockIdx.x < 48) {
    // ===================== SCAN ROLE =======================================
    const int l = blockIdx.x >> 4;
    const int c = s - 2 * l;
    if (c < 0 || c >= cpl) return;

    const unsigned short* Whp_s = Whp + (size_t)l * G3_ * H_;
    const float* bhh_s = bhh_all + (size_t)l * G3_;
    float* hb = hbuf + (size_t)l * B_ * H_;
    const float* gx_r = gxbase + (size_t)(2 * l + (c & 1)) * gx_elems;
    const int t0s = c * CH;
    const int lastL = (l == 2) ? 1 : 0;

    unsigned short* WhN  = lds_;                 // [16 w][8 kc][512] = 128KB
    unsigned short* Abuf = lds_ + 65536;         // [2][8 kc][512] = 16KB

    const int bid = blockIdx.x & 15;
    const int b0  = bid * 16;
    const int bb  = fr;

    const s8v* WhpV = (const s8v*)Whp_s;

    s8v whr[8], whz[8];
    #pragma unroll
    for (int kc = 0; kc < 8; ++kc) {
      whr[kc] = WhpV[((     wid) * 8 + kc) * 64 + lane];
      whz[kc] = WhpV[((16 + wid) * 8 + kc) * 64 + lane];
    }
    #pragma unroll
    for (int kc = 0; kc < 8; ++kc) {
      s8v v = WhpV[((32 + wid) * 8 + kc) * 64 + lane];
      *(s8v*)&WhN[(wid * 8 + kc) * 512 + lane * 8] = v;
    }

    const int u0 = 16 * wid + 4 * fq;
    const f4r bhn4 = *(const f4r*)&bhh_s[2 * H_ + u0];

    f4r hn4 = {0.f, 0.f, 0.f, 0.f};
    if (t0s != 0) hn4 = *(const f4r*)&hb[(size_t)(b0 + bb) * H_ + u0];

    const int kcw  = wid >> 1;
    const int lp   = bb | (((2 * wid + (fq >> 1)) & 3) << 4);
    const int eo   = (fq & 1) * 4;
    const int aoff = kcw * 512 + lp * 8 + eo;

    {
      s4v hh;
      #pragma unroll
      for (int j = 0; j < 4; ++j) hh[j] = (short)f2bf(hn4[j]);
      *(s4v*)&Abuf[aoff] = hh;
    }

    // preload gx(t=0) into current regs (gx_r ready since previous dispatch)
    const float* gb0 = gx_r + ((size_t)(b0 + bb) * CH) * G3_;
    f4r xr4 = *(const f4r*)(gb0 + u0);
    f4r xz4 = *(const f4r*)(gb0 + H_ + u0);
    f4r xn4 = *(const f4r*)(gb0 + 2 * H_ + u0);

    int cur = 0;
    for (int t = 0; t < CH; ++t) {
      __syncthreads();   // Abuf[cur] (and WhN at t=0) visible

      // prefetch gx(t+1): full step of MFMA+epilogue hides its latency
      const int tn = (t + 1 < CH) ? t + 1 : t;
      const float* gbn = gx_r + ((size_t)(b0 + bb) * CH + tn) * G3_;
      f4r xr_n = *(const f4r*)(gbn + u0);
      f4r xz_n = *(const f4r*)(gbn + H_ + u0);
      f4r xn_n = *(const f4r*)(gbn + 2 * H_ + u0);

      f4v accR = {}, accZ = {}, accN = {};
      #pragma unroll
      for (int kc = 0; kc < 8; ++kc) {
        s8v ahh = *(const s8v*)&Abuf[cur * 4096 + kc * 512 + lane * 8];
        s8v wn  = *(const s8v*)&WhN[(wid * 8 + kc) * 512 + lane * 8];
        accR = MF(whr[kc], ahh, accR);
        accZ = MF(whz[kc], ahh, accZ);
        accN = MF(wn,      ahh, accN);
      }

      #pragma unroll
      for (int i = 0; i < 4; ++i) {
        const float r = sigm(xr4[i] + accR[i]);
        const float z = sigm(xz4[i] + accZ[i]);
        const float n = tanh_f(xn4[i] + r * (accN[i] + bhn4[i]));
        hn4[i] = (1.f - z) * n + z * hn4[i];
      }
      if (!lastL) {
        __builtin_nontemporal_store(
            hn4, (f4r*)&y[((size_t)(b0 + bb) * S_ + (t0s + t)) * H_ + u0]);
      }
      {
        s4v hh;
        #pragma unroll
        for (int j = 0; j < 4; ++j) hh[j] = (short)f2bf(hn4[j]);
        *(s4v*)&Abuf[(cur ^ 1) * 4096 + aoff] = hh;
      }
      xr4 = xr_n; xz4 = xz_n; xn4 = xn_n;
      cur ^= 1;
    }

    *(f4r*)&hb[(size_t)(b0 + bb) * H_ + u0] = hn4;

  } else {
    // ===================== GEMM ROLE =======================================
    const int g = blockIdx.x - 48;
    const int per = CH * 12;
    const int l = g / per;
    if (l >= 3) return;
    const int c2 = s + 1 - 2 * l;
    if (c2 < 0 || c2 >= cpl) return;

    const int gidx  = g % per;
    const int mtile = gidx / 12, gtile = gidx % 12;
    const int r0 = mtile * 256, g0 = gtile * 64;

    const float* A    = (l == 0) ? x : y;
    const int    K    = (l == 0) ? D_ : H_;
    const float* Wih  = (l == 0) ? W_ih0 : (W_ihr + (size_t)(l - 1) * G3_ * H_);
    const float* b2g  = bias2 + l * 768;
    float* gx_w = gxbase + (size_t)(2 * l + (c2 & 1)) * gx_elems;
    const int t0g = c2 * CH;

    unsigned short* Ah = lds_;            // [256][40] ushort
    unsigned short* Wh = lds_ + 10240;    // [64][40]

    const int row = tid >> 2;
    const int ks  = (tid & 3) * 8;
    const int CHm1 = CH - 1;
    const int r = r0 + row;
    const int rg = ((r >> chsh) * S_) + t0g + (r & CHm1);
    const float* ap = A + (size_t)rg * K + ks;
    const float* wp = Wih + (size_t)(g0 + (row & 63)) * K + ks;

    f4v acc[4] = {};

    for (int k0 = 0; k0 < K; k0 += 32) {
      float4 a0 = *(const float4*)(ap + k0);
      float4 a1 = *(const float4*)(ap + k0 + 4);
      float4 w0, w1;
      if (tid < 256) {
        w0 = *(const float4*)(wp + k0);
        w1 = *(const float4*)(wp + k0 + 4);
      }
      __syncthreads();
      {
        float av[8] = {a0.x,a0.y,a0.z,a0.w,a1.x,a1.y,a1.z,a1.w};
        unsigned short ah8[8];
        #pragma unroll
        for (int i = 0; i < 8; ++i) ah8[i] = f2bf(av[i]);
        *(s8v*)&Ah[row * 40 + ks] = *(s8v*)ah8;
        if (tid < 256) {
          float wv[8] = {w0.x,w0.y,w0.z,w0.w,w1.x,w1.y,w1.z,w1.w};
          unsigned short wh8[8];
          #pragma unroll
          for (int i = 0; i < 8; ++i) wh8[i] = f2bf(wv[i]);
          *(s8v*)&Wh[row * 40 + ks] = *(s8v*)wh8;
        }
      }
      __syncthreads();

      s8v a_hi = *(const s8v*)&Ah[(16 * wid + fr) * 40 + fq * 8];
      #pragma unroll
      for (int c = 0; c < 4; ++c) {
        s8v b_hi = *(const s8v*)&Wh[(c * 16 + fr) * 40 + fq * 8];
        acc[c] = MF(a_hi, b_hi, acc[c]);
      }
    }

    const int orow = r0 + wid * 16 + fq * 4;
    #pragma unroll
    for (int c = 0; c < 4; ++c) {
      const float bi = b2g[g0 + c * 16 + fr];
      #pragma unroll
      for (int i = 0; i < 4; ++i) {
        gx_w[(size_t)(orow + i) * G3_ + g0 + c * 16 + fr] = acc[c][i] + bi;
      }
    }
  }
}

// ---------------------------------------------------------------------------
// Head: LayerNorm(h_last) -> MLP 256->32 (ReLU) -> 32->1. One wave per batch.
// ---------------------------------------------------------------------------
__global__ __launch_bounds__(64) void head_kernel(
    const float* __restrict__ hlast, const float* __restrict__ lng,
    const float* __restrict__ lnb, const float* __restrict__ W1,
    const float* __restrict__ b1, const float* __restrict__ W2,
    const float* __restrict__ b2, float* __restrict__ out)
{
  const int b = blockIdx.x;
  const int lane = threadIdx.x;
  float4 v = *(const float4*)&hlast[(size_t)b * H_ + lane * 4];
  float s = v.x + v.y + v.z + v.w;
  #pragma unroll
  for (int m = 32; m > 0; m >>= 1) s += __shfl_xor(s, m, 64);
  const float mu = s * (1.f / 256.f);
  const float dx = v.x - mu, dy = v.y - mu, dz = v.z - mu, dw = v.w - mu;
  float q = dx*dx + dy*dy + dz*dz + dw*dw;
  #pragma unroll
  for (int m = 32; m > 0; m >>= 1) q += __shfl_xor(q, m, 64);
  const float rstd = rsqrtf(q * (1.f / 256.f) + 1e-5f);

  __shared__ float ln[256];
  const int i4 = lane * 4;
  ln[i4 + 0] = dx * rstd * lng[i4 + 0] + lnb[i4 + 0];
  ln[i4 + 1] = dy * rstd * lng[i4 + 1] + lnb[i4 + 1];
  ln[i4 + 2] = dz * rstd * lng[i4 + 2] + lnb[i4 + 2];
  ln[i4 + 3] = dw * rstd * lng[i4 + 3] + lnb[i4 + 3];
  __syncthreads();

  float hd = 0.f;
  if (lane < 32) {
    const float* w = W1 + (size_t)lane * H_;
    float a = 0.f;
    for (int k = 0; k < H_; ++k) a += ln[k] * w[k];
    a += b1[lane];
    hd = fmaxf(a, 0.f) * W2[lane];
  }
  #pragma unroll
  for (int m = 16; m > 0; m >>= 1) hd += __shfl_xor(hd, m, 64);
  if (lane == 0) out[b] = hd + b2[0];
}

// ---------------------------------------------------------------------------
extern "C" void kernel_launch(void* const* d_in, const int* in_sizes, int n_in,
                              void* d_out, int out_size, void* d_ws, size_t ws_size,
                              hipStream_t stream)
{
  const float* x     = (const float*)d_in[0];
  const float* W_ih0 = (const float*)d_in[1];
  const float* W_ihr = (const float*)d_in[2];
  const float* W_hh  = (const float*)d_in[3];
  const float* b_ih  = (const float*)d_in[4];
  const float* b_hh  = (const float*)d_in[5];
  const float* lng   = (const float*)d_in[6];
  const float* lnb   = (const float*)d_in[7];
  const float* W1    = (const float*)d_in[8];
  const float* b1    = (const float*)d_in[9];
  const float* W2    = (const float*)d_in[10];
  const float* b2    = (const float*)d_in[11];
  float* out = (float*)d_out;

  const size_t y_elems   = (size_t)B_ * S_ * H_;
  const size_t h_elems   = (size_t)B_ * H_;
  const size_t whp_elems = (size_t)G3_ * H_;

  // CH: largest chunk s.t. y + 6 gx buffers + 3 hbuf + packs fit in ws
  int CH = 64;
  while (CH > 8) {
    size_t need = (y_elems + 6 * (size_t)B_ * CH * G3_ + 3 * h_elems + 3 * 768) * 4
                + 3 * whp_elems * 2 + 4096;
    if (need <= ws_size) break;
    CH >>= 1;
  }
  const int chsh = __builtin_ctz((unsigned)CH);
  const size_t gx_elems = (size_t)B_ * CH * G3_;
  const int cpl = S_ / CH;

  float* y      = (float*)d_ws;
  float* gxbase = y + y_elems;
  float* hbuf   = gxbase + 6 * gx_elems;
  unsigned short* Whp = (unsigned short*)(hbuf + 3 * h_elems);
  float* bias2 = (float*)(Whp + 3 * whp_elems);

  const size_t lds_bytes = 131072 + 16384;   // 144 KiB
  const int grid = 48 + 3 * CH * 12;

  for (int l = 0; l < 3; ++l) {
    pack_whh<<<dim3(48, 8), 64, 0, stream>>>(
        W_hh + (size_t)l * G3_ * H_, Whp + (size_t)l * whp_elems,
        b_ih + (size_t)l * G3_, b_hh + (size_t)l * G3_, bias2 + l * 768);
  }

  for (int s = -1; s <= cpl + 3; ++s) {
    fused_step<<<grid, 1024, lds_bytes, stream>>>(
        s, CH, chsh, cpl, x, y, W_ih0, W_ihr, Whp, b_hh, bias2, gxbase, hbuf);
  }

  head_kernel<<<256, 64, 0, stream>>>(hbuf + 2 * h_elems, lng, lnb,
                                      W1, b1, W2, b2, out);
}